// Round 8
// baseline (42.543 us; speedup 1.0000x reference)
//
#include <hip/hip_runtime.h>
#include <hip/hip_bf16.h>

// Problem: B=16384, I=512, H=512.
// Output = modrelu(complex(inputs@w_ih.T [:, :512], [:, 512:]), b_h)
// The FFT/reflect/perm state path in the reference is DEAD CODE (preact unused).
//
// Two-pass: (1) cvt A+W -> bf16; (2) 128x128-tile MFMA GEMM with fused modReLU,
// LDS-coalesced full-line output stores (the R1-R5 bottleneck was 64B-scattered
// epilogue stores running at ~25% of HBM write peak).

typedef __attribute__((ext_vector_type(8))) short bf16x8;
typedef __attribute__((ext_vector_type(4))) float f32x4;

#define BM 128            // M rows per block
#define BK 64             // K per tile
#define KDIM 512
#define NDIM 1024
#define NKT 8

#define VMCNT(n) asm volatile("s_waitcnt vmcnt(" #n ")" ::: "memory")
#define LGKM(n)  asm volatile("s_waitcnt lgkmcnt(" #n ")" ::: "memory")

__device__ __forceinline__ unsigned short f2bf(float f) {
    unsigned u = __builtin_bit_cast(unsigned, f);
    u += 0x7fffu + ((u >> 16) & 1u);   // round-to-nearest-even
    return (unsigned short)(u >> 16);
}

// single conversion dispatch for both A and W
__global__ __launch_bounds__(256) void cvt_both(
    const float* __restrict__ A, const float* __restrict__ W,
    unsigned short* __restrict__ Abf, unsigned short* __restrict__ Wbf,
    int nA4, int nTot4) {
    int i = blockIdx.x * blockDim.x + threadIdx.x;
    int stride = gridDim.x * blockDim.x;
    for (; i < nTot4; i += stride) {
        float4 v;
        if (i < nA4) v = reinterpret_cast<const float4*>(A)[i];
        else         v = reinterpret_cast<const float4*>(W)[i - nA4];
        ushort4 o;
        o.x = f2bf(v.x); o.y = f2bf(v.y); o.z = f2bf(v.z); o.w = f2bf(v.w);
        if (i < nA4) reinterpret_cast<ushort4*>(Abf)[i] = o;
        else         reinterpret_cast<ushort4*>(Wbf)[i - nA4] = o;
    }
}

__device__ __forceinline__ void gload_lds16(const void* g, void* l) {
    __builtin_amdgcn_global_load_lds(
        (const __attribute__((address_space(1))) unsigned int*)g,
        (__attribute__((address_space(3))) unsigned int*)l, 16, 0, 0);
}

// 128 M-rows x 64 re/im col-pairs per block. 4 waves 2M x 2N; per wave
// 64 rows x 32 pairs: acc[4][4] (j 0..1 re, j 2..3 im).
// B-tile rows 0..63 = W[cb*64+r] (re), 64..127 = W[512+cb*64+r] (im).
__global__ __launch_bounds__(256, 2) void gemm_modrelu(
    const unsigned short* __restrict__ A,   // 16384 x 512 bf16
    const unsigned short* __restrict__ W,   // 1024 x 512 bf16
    const float* __restrict__ bh,           // 512 f32
    float* __restrict__ out)                // 16384 x 1024 f32
{
    // 64 KiB LDS, exactly 2 blocks/CU. Reused as the 128x128 f32 out-tile
    // in the epilogue.
    __shared__ __align__(16) char smem[65536];
    unsigned short* At0 = (unsigned short*)smem;            // [2][128*64]
    unsigned short* Bt0 = (unsigned short*)(smem + 32768);  // [2][128*64]
    float* C = (float*)smem;                                // [128][128]

    const int tid = threadIdx.x;
    const int w   = tid >> 6;
    const int l   = tid & 63;
    const int l15 = l & 15;
    const int l4  = l >> 4;
    const int wm  = w >> 1;        // 0..1 : 64-row half
    const int wn  = w & 1;         // 0..1 : 32-pair half

    // T1: XCD-chunked swizzle. 1024 blocks, 128/XCD, cb fastest: the 8 sharers
    // of each A panel run on one XCD (1 HBM fetch + 7 L2 hits).
    const int bx = blockIdx.x;
    const int lg = (bx & 7) * 128 + (bx >> 3);
    const int mb = lg >> 3;        // 128 m-blocks of 128 rows
    const int cb = lg & 7;         // 8 col-blocks of 64 pairs

    // staging: wave w stages rows [w*32, +32) of each tile, 4 issues x 8 rows;
    // lane l -> row off (l>>3), physical 16B slot (l&7), source pre-swizzled (T2).
    const int srow = l >> 3;
    const int sseg = (l & 7) ^ srow;
    const unsigned short* ga[4];
    const unsigned short* gb[4];
    int ldso[4];
#pragma unroll
    for (int is = 0; is < 4; ++is) {
        int row  = w * 32 + is * 8 + srow;
        ga[is]   = A + (size_t)(mb * BM + row) * KDIM + sseg * 8;
        int wrow = (row >> 6) * 512 + cb * 64 + (row & 63);
        gb[is]   = W + (size_t)wrow * KDIM + sseg * 8;
        ldso[is] = (w * 32 + is * 8) * BK;   // wave-uniform LDS base (shorts)
    }

    auto stage = [&](int kt, int buf) {
        unsigned short* at = At0 + buf * (BM * BK);
        unsigned short* bt = Bt0 + buf * (BM * BK);
#pragma unroll
        for (int is = 0; is < 4; ++is)
            gload_lds16(ga[is] + kt * BK, at + ldso[is]);
#pragma unroll
        for (int is = 0; is < 4; ++is)
            gload_lds16(gb[is] + kt * BK, bt + ldso[is]);
    };

    f32x4 acc[4][4];
#pragma unroll
    for (int i = 0; i < 4; ++i)
#pragma unroll
        for (int j = 0; j < 4; ++j) acc[i][j] = f32x4{0.f, 0.f, 0.f, 0.f};

    // prologue: tiles 0 and 1 in flight (8 vmem ops each)
    stage(0, 0);
    stage(1, 1);
    VMCNT(8);                       // tile 0 resident
    __builtin_amdgcn_s_barrier();

#pragma unroll
    for (int kt = 0; kt < NKT; ++kt) {
        const int buf = kt & 1;
        const unsigned short* at = At0 + buf * (BM * BK);
        const unsigned short* bt = Bt0 + buf * (BM * BK);

#pragma unroll
        for (int ks = 0; ks < 2; ++ks) {
            bf16x8 af[4], bf[4];
#pragma unroll
            for (int i = 0; i < 4; ++i) {
                int row = wm * 64 + i * 16 + l15;
                af[i] = *(const bf16x8*)(&at[row * BK + (((ks * 4 + l4) ^ (row & 7)) * 8)]);
            }
#pragma unroll
            for (int j = 0; j < 4; ++j) {
                int row = (j >> 1) * 64 + wn * 32 + (j & 1) * 16 + l15;
                bf[j] = *(const bf16x8*)(&bt[row * BK + (((ks * 4 + l4) ^ (row & 7)) * 8)]);
            }
            LGKM(0);
            __builtin_amdgcn_sched_barrier(0);
            __builtin_amdgcn_s_setprio(1);
#pragma unroll
            for (int i = 0; i < 4; ++i)
#pragma unroll
                for (int j = 0; j < 4; ++j)
                    acc[i][j] = __builtin_amdgcn_mfma_f32_16x16x32_bf16(
                        af[i], bf[j], acc[i][j], 0, 0, 0);
            __builtin_amdgcn_s_setprio(0);
        }

        if (kt + 1 < NKT) {
            __builtin_amdgcn_s_barrier();          // all waves done reading buf
            if (kt + 2 < NKT) {
                stage(kt + 2, buf);                // overwrite buf with tile kt+2
                VMCNT(8);                          // tile kt+1 landed, kt+2 in flight
            } else {
                VMCNT(0);                          // tail: drain tile kt+1
            }
            __builtin_amdgcn_s_barrier();          // tile kt+1 visible to all
        }
    }

    // ---- fused modReLU + LDS-coalesced store epilogue ----
    // C/D layout (m89): col = lane&15 (n), row = (lane>>4)*4 + jj (m)
    __syncthreads();                               // K-loop LDS reads all done
#pragma unroll
    for (int j = 0; j < 2; ++j) {                  // pair fragments (re j, im j+2)
        int col = wn * 32 + j * 16 + l15;          // local pair index 0..63
        float b = bh[cb * 64 + col];
#pragma unroll
        for (int i = 0; i < 4; ++i) {
#pragma unroll
            for (int jj = 0; jj < 4; ++jj) {
                int rowl = wm * 64 + i * 16 + l4 * 4 + jj;
                float re  = acc[i][j][jj];
                float imv = acc[i][j + 2][jj];
                float norm  = sqrtf(re * re + imv * imv);
                float scale = fmaxf(norm + b, 0.f) * __builtin_amdgcn_rcpf(norm + 1e-6f);
                C[rowl * 128 + col]      = re  * scale;   // cols 0..63  = re
                C[rowl * 128 + 64 + col] = imv * scale;   // cols 64..127 = im
            }
        }
    }
    __syncthreads();

    // flat re-read: one C row = 128 floats = 32 f32x4 segments; 32 lanes cover
    // a full row (lanes 0..15 -> re cols 0..63, lanes 16..31 -> im cols 64..127),
    // 2 rows per instruction -> contiguous 256B runs per half = full-line writes.
    const int seg   = l & 31;
    const int rhalf = l >> 5;
#pragma unroll
    for (int it = 0; it < 16; ++it) {
        int rowl = w * 32 + it * 2 + rhalf;
        f32x4 v = *reinterpret_cast<const f32x4*>(&C[rowl * 128 + seg * 4]);
        size_t m = (size_t)(mb * BM + rowl);
        int n = (seg < 16) ? (cb * 64 + seg * 4)
                           : (512 + cb * 64 + (seg - 16) * 4);
        __builtin_nontemporal_store(v, reinterpret_cast<f32x4*>(out + m * NDIM + n));
    }
}

extern "C" void kernel_launch(void* const* d_in, const int* in_sizes, int n_in,
                              void* d_out, int out_size, void* d_ws, size_t ws_size,
                              hipStream_t stream) {
    const float* inputs = (const float*)d_in[0];   // (16384, 512) f32
    const float* w_ih   = (const float*)d_in[2];   // (1024, 512)  f32
    const float* b_h    = (const float*)d_in[3];   // (512,)       f32
    float* out = (float*)d_out;                    // (16384, 1024) f32

    unsigned short* Abf = (unsigned short*)d_ws;                          // 16 MiB
    unsigned short* Wbf = (unsigned short*)((char*)d_ws + (size_t)16384 * 512 * 2);

    const int nA4 = (16384 * 512) / 4;
    const int nW4 = (1024 * 512) / 4;
    cvt_both<<<2048, 256, 0, stream>>>(inputs, w_ih, Abf, Wbf, nA4, nA4 + nW4);

    // 128 m-blocks x 8 col-blocks = 1024 blocks, 2 resident/CU
    gemm_modrelu<<<1024, 256, 0, stream>>>(Abf, Wbf, b_h, out);
}